// Round 1
// baseline (1337.868 us; speedup 1.0000x reference)
//
#include <hip/hip_runtime.h>

typedef unsigned int u32;
typedef unsigned short u16;

#define T_ 2048
#define HEADS 16
#define DH 64
#define NQ (2 * HEADS * T_ * DH)  // 4194304 elems per tensor

__device__ __forceinline__ float bflo(u32 u) {
    union { u32 uu; float f; } x; x.uu = u << 16; return x.f;
}
__device__ __forceinline__ float bfhi(u32 u) {
    union { u32 uu; float f; } x; x.uu = u & 0xffff0000u; return x.f;
}
__device__ __forceinline__ u16 f2bf(float f) {
    union { float f; u32 u; } x; x.f = f;
    return (u16)((x.u + 0x7fffu + ((x.u >> 16) & 1u)) >> 16);
}

// ---------------- QKV projection: qkv = x @ W_attn^T + b_attn ----------------
// C[m][n] = sum_k x[m][k] * W[n][k];  scatter into q/k/v [B,H,T,D] as bf16.
__global__ __launch_bounds__(256) void qkv_gemm(
    const float* __restrict__ x, const float* __restrict__ W,
    const float* __restrict__ bias,
    u16* __restrict__ q, u16* __restrict__ k, u16* __restrict__ v)
{
    __shared__ float As[16][68];
    __shared__ float Bs[16][68];
    const int tid = threadIdx.x;
    const int m0 = blockIdx.y * 64;
    const int n0 = blockIdx.x * 64;
    const int ty = tid >> 4, tx = tid & 15;
    const int lm = tid >> 2;          // 0..63 row for loads
    const int lk = (tid & 3) << 2;    // k offset (float4)
    float acc[4][4] = {{0.f}};
    for (int k0 = 0; k0 < 1024; k0 += 16) {
        float4 a4 = *(const float4*)&x[(m0 + lm) * 1024 + k0 + lk];
        float4 b4 = *(const float4*)&W[(n0 + lm) * 1024 + k0 + lk];
        __syncthreads();
        As[lk + 0][lm] = a4.x; As[lk + 1][lm] = a4.y;
        As[lk + 2][lm] = a4.z; As[lk + 3][lm] = a4.w;
        Bs[lk + 0][lm] = b4.x; Bs[lk + 1][lm] = b4.y;
        Bs[lk + 2][lm] = b4.z; Bs[lk + 3][lm] = b4.w;
        __syncthreads();
        #pragma unroll
        for (int kk = 0; kk < 16; ++kk) {
            float4 a = *(const float4*)&As[kk][ty * 4];
            float4 b = *(const float4*)&Bs[kk][tx * 4];
            float av[4] = {a.x, a.y, a.z, a.w};
            float bv[4] = {b.x, b.y, b.z, b.w};
            #pragma unroll
            for (int i = 0; i < 4; ++i)
                #pragma unroll
                for (int j = 0; j < 4; ++j)
                    acc[i][j] += av[i] * bv[j];
        }
    }
    #pragma unroll
    for (int i = 0; i < 4; ++i) {
        const int m = m0 + ty * 4 + i;
        const int bb = m >> 11, t = m & 2047;
        #pragma unroll
        for (int j = 0; j < 4; ++j) {
            const int n = n0 + tx * 4 + j;
            const float val = acc[i][j] + bias[n];
            const int part = n >> 10, c = n & 1023;
            const int h = c >> 6, d = c & 63;
            u16* dst = (part == 0) ? q : (part == 1) ? k : v;
            dst[(((bb << 4) + h) * T_ + t) * DH + d] = f2bf(val);
        }
    }
}

// ---------------- flash attention: one block per (bh, 64-row q tile) ----------------
#define UNPACK8(dst, off, u) \
    dst[(off)+0]=bflo(u.x); dst[(off)+1]=bfhi(u.x); dst[(off)+2]=bflo(u.y); dst[(off)+3]=bfhi(u.y); \
    dst[(off)+4]=bflo(u.z); dst[(off)+5]=bfhi(u.z); dst[(off)+6]=bflo(u.w); dst[(off)+7]=bfhi(u.w);

__global__ __launch_bounds__(256) void flash_attn(
    const u16* __restrict__ Q, const u16* __restrict__ K,
    const u16* __restrict__ V, u16* __restrict__ Y)
{
    __shared__ float Kt[64][68];  // [d][j]  (transposed K tile)
    __shared__ float Vs[64][68];  // [j][d]
    __shared__ float Ps[64][68];  // [r][j]
    const int qt = blockIdx.x, bh = blockIdx.y;
    const int tid = threadIdx.x;
    const int r = tid >> 2, sub = tid & 3;
    const u16* Qb = Q + bh * (T_ * DH);
    const u16* Kb = K + bh * (T_ * DH);
    const u16* Vb = V + bh * (T_ * DH);
    const int qrow = qt * 64 + r;

    float qreg[64];
    {
        const uint4* qp = (const uint4*)(Qb + qrow * DH);
        #pragma unroll
        for (int c = 0; c < 8; ++c) {
            uint4 u = qp[c];
            float tmp[8];
            UNPACK8(tmp, 0, u);
            #pragma unroll
            for (int i = 0; i < 8; ++i) qreg[c * 8 + i] = tmp[i] * 0.125f;
        }
    }
    float o[16];
    #pragma unroll
    for (int i = 0; i < 16; ++i) o[i] = 0.f;
    float m_r = -INFINITY, l_r = 0.f;

    for (int kt = 0; kt <= qt; ++kt) {
        const uint4* kp = (const uint4*)(Kb + (kt * 64 + r) * DH + sub * 16);
        const uint4* vp = (const uint4*)(Vb + (kt * 64 + r) * DH + sub * 16);
        uint4 ku0 = kp[0], ku1 = kp[1];
        uint4 vu0 = vp[0], vu1 = vp[1];
        float kf[16], vf[16];
        UNPACK8(kf, 0, ku0); UNPACK8(kf, 8, ku1);
        UNPACK8(vf, 0, vu0); UNPACK8(vf, 8, vu1);
        __syncthreads();  // prev tile fully consumed before overwrite
        *(float4*)&Vs[r][sub * 16 + 0]  = make_float4(vf[0], vf[1], vf[2], vf[3]);
        *(float4*)&Vs[r][sub * 16 + 4]  = make_float4(vf[4], vf[5], vf[6], vf[7]);
        *(float4*)&Vs[r][sub * 16 + 8]  = make_float4(vf[8], vf[9], vf[10], vf[11]);
        *(float4*)&Vs[r][sub * 16 + 12] = make_float4(vf[12], vf[13], vf[14], vf[15]);
        #pragma unroll
        for (int i = 0; i < 16; ++i) Kt[sub * 16 + i][r] = kf[i];
        __syncthreads();  // tiles ready

        // S = q . k  (pre-scaled q)
        float s[16];
        #pragma unroll
        for (int i = 0; i < 16; ++i) s[i] = 0.f;
        #pragma unroll
        for (int d = 0; d < 64; ++d) {
            const float qd = qreg[d];
            const float4* kp4 = (const float4*)&Kt[d][sub * 16];
            float4 a = kp4[0], b = kp4[1], c = kp4[2], e = kp4[3];
            s[0] += qd * a.x; s[1] += qd * a.y; s[2]  += qd * a.z; s[3]  += qd * a.w;
            s[4] += qd * b.x; s[5] += qd * b.y; s[6]  += qd * b.z; s[7]  += qd * b.w;
            s[8] += qd * c.x; s[9] += qd * c.y; s[10] += qd * c.z; s[11] += qd * c.w;
            s[12]+= qd * e.x; s[13]+= qd * e.y; s[14] += qd * e.z; s[15] += qd * e.w;
        }
        if (kt == qt) {
            #pragma unroll
            for (int jj = 0; jj < 16; ++jj)
                if (sub * 16 + jj > r) s[jj] = -INFINITY;
        }
        // online softmax (4 lanes per row)
        float tm = s[0];
        #pragma unroll
        for (int jj = 1; jj < 16; ++jj) tm = fmaxf(tm, s[jj]);
        tm = fmaxf(tm, __shfl_xor(tm, 1));
        tm = fmaxf(tm, __shfl_xor(tm, 2));
        const float mnew = fmaxf(m_r, tm);
        float p[16]; float ps = 0.f;
        #pragma unroll
        for (int jj = 0; jj < 16; ++jj) { p[jj] = __expf(s[jj] - mnew); ps += p[jj]; }
        ps += __shfl_xor(ps, 1);
        ps += __shfl_xor(ps, 2);
        const float corr = __expf(m_r - mnew);
        l_r = l_r * corr + ps;
        m_r = mnew;
        #pragma unroll
        for (int i = 0; i < 16; ++i) o[i] *= corr;
        *(float4*)&Ps[r][sub * 16 + 0]  = make_float4(p[0], p[1], p[2], p[3]);
        *(float4*)&Ps[r][sub * 16 + 4]  = make_float4(p[4], p[5], p[6], p[7]);
        *(float4*)&Ps[r][sub * 16 + 8]  = make_float4(p[8], p[9], p[10], p[11]);
        *(float4*)&Ps[r][sub * 16 + 12] = make_float4(p[12], p[13], p[14], p[15]);
        __syncthreads();  // Ps visible

        // O += P @ V
        #pragma unroll 8
        for (int j = 0; j < 64; ++j) {
            const float pp = Ps[r][j];
            const float4* vp4 = (const float4*)&Vs[j][sub * 16];
            float4 a = vp4[0], b = vp4[1], c = vp4[2], e = vp4[3];
            o[0] += pp * a.x; o[1] += pp * a.y; o[2]  += pp * a.z; o[3]  += pp * a.w;
            o[4] += pp * b.x; o[5] += pp * b.y; o[6]  += pp * b.z; o[7]  += pp * b.w;
            o[8] += pp * c.x; o[9] += pp * c.y; o[10] += pp * c.z; o[11] += pp * c.w;
            o[12]+= pp * e.x; o[13]+= pp * e.y; o[14] += pp * e.z; o[15] += pp * e.w;
        }
    }
    const float inv = 1.0f / l_r;
    u32 w[8];
    #pragma unroll
    for (int c2 = 0; c2 < 8; ++c2)
        w[c2] = (u32)f2bf(o[2 * c2] * inv) | ((u32)f2bf(o[2 * c2 + 1] * inv) << 16);
    uint4* yp = (uint4*)(Y + bh * (T_ * DH) + qrow * DH + sub * 16);
    yp[0] = make_uint4(w[0], w[1], w[2], w[3]);
    yp[1] = make_uint4(w[4], w[5], w[6], w[7]);
}

// ---------------- output projection: out = Y @ W_proj^T + b_proj ----------------
__global__ __launch_bounds__(256) void proj_gemm(
    const u16* __restrict__ Y, const float* __restrict__ W,
    const float* __restrict__ bias, float* __restrict__ out)
{
    __shared__ float As[16][68];
    __shared__ float Bs[16][68];
    const int tid = threadIdx.x;
    const int m0 = blockIdx.y * 64;
    const int n0 = blockIdx.x * 64;
    const int ty = tid >> 4, tx = tid & 15;
    const int lm = tid >> 2;
    const int lk = (tid & 3) << 2;
    const int m = m0 + lm;
    const int bb = m >> 11, t = m & 2047;
    float acc[4][4] = {{0.f}};
    for (int k0 = 0; k0 < 1024; k0 += 16) {
        const int kcol = k0 + lk;
        const int h = kcol >> 6, dd = kcol & 63;
        uint2 u = *(const uint2*)&Y[(((bb << 4) + h) * T_ + t) * DH + dd];
        float4 b4 = *(const float4*)&W[(n0 + lm) * 1024 + kcol];
        __syncthreads();
        As[lk + 0][lm] = bflo(u.x); As[lk + 1][lm] = bfhi(u.x);
        As[lk + 2][lm] = bflo(u.y); As[lk + 3][lm] = bfhi(u.y);
        Bs[lk + 0][lm] = b4.x; Bs[lk + 1][lm] = b4.y;
        Bs[lk + 2][lm] = b4.z; Bs[lk + 3][lm] = b4.w;
        __syncthreads();
        #pragma unroll
        for (int kk = 0; kk < 16; ++kk) {
            float4 a = *(const float4*)&As[kk][ty * 4];
            float4 b = *(const float4*)&Bs[kk][tx * 4];
            float av[4] = {a.x, a.y, a.z, a.w};
            float bv[4] = {b.x, b.y, b.z, b.w};
            #pragma unroll
            for (int i = 0; i < 4; ++i)
                #pragma unroll
                for (int j = 0; j < 4; ++j)
                    acc[i][j] += av[i] * bv[j];
        }
    }
    #pragma unroll
    for (int i = 0; i < 4; ++i) {
        const int mm = m0 + ty * 4 + i;
        #pragma unroll
        for (int j = 0; j < 4; ++j) {
            const int n = n0 + tx * 4 + j;
            out[mm * 1024 + n] = acc[i][j] + bias[n];
        }
    }
}

extern "C" void kernel_launch(void* const* d_in, const int* in_sizes, int n_in,
                              void* d_out, int out_size, void* d_ws, size_t ws_size,
                              hipStream_t stream) {
    const float* x      = (const float*)d_in[0];
    const float* W_attn = (const float*)d_in[1];
    const float* b_attn = (const float*)d_in[2];
    const float* W_proj = (const float*)d_in[3];
    const float* b_proj = (const float*)d_in[4];
    float* out = (float*)d_out;

    u16* q = (u16*)d_ws;       // each NQ elems (8 MB)
    u16* k = q + NQ;
    u16* v = k + NQ;
    u16* y = v + NQ;

    qkv_gemm<<<dim3(48, 64), 256, 0, stream>>>(x, W_attn, b_attn, q, k, v);
    flash_attn<<<dim3(32, 32), 256, 0, stream>>>(q, k, v, y);
    proj_gemm<<<dim3(16, 64), 256, 0, stream>>>(y, W_proj, b_proj, out);
}

// Round 2
// 579.118 us; speedup vs baseline: 2.3102x; 2.3102x over previous
//
#include <hip/hip_runtime.h>

typedef unsigned int u32;
typedef unsigned short u16;
typedef __attribute__((ext_vector_type(8))) short bf16x8;
typedef __attribute__((ext_vector_type(4))) float f32x4;

#define T_ 2048
#define HEADS 16
#define DH 64
#define NQ (2 * HEADS * T_ * DH)  // 4194304 elems per tensor

__device__ __forceinline__ float bflo(u32 u) {
    union { u32 uu; float f; } x; x.uu = u << 16; return x.f;
}
__device__ __forceinline__ float bfhi(u32 u) {
    union { u32 uu; float f; } x; x.uu = u & 0xffff0000u; return x.f;
}
__device__ __forceinline__ u16 f2bf(float f) {
    union { float f; u32 u; } x; x.f = f;
    return (u16)((x.u + 0x7fffu + ((x.u >> 16) & 1u)) >> 16);
}

// ---------------- QKV projection: qkv = x @ W_attn^T + b_attn ----------------
// C[m][n] = sum_k x[m][k] * W[n][k];  scatter into q/k/v [B,H,T,D] as bf16.
// q is pre-scaled by 1/sqrt(D) = 0.125 (exact power of 2).
__global__ __launch_bounds__(256) void qkv_gemm(
    const float* __restrict__ x, const float* __restrict__ W,
    const float* __restrict__ bias,
    u16* __restrict__ q, u16* __restrict__ k, u16* __restrict__ v)
{
    __shared__ float As[16][68];
    __shared__ float Bs[16][68];
    const int tid = threadIdx.x;
    const int m0 = blockIdx.y * 64;
    const int n0 = blockIdx.x * 64;
    const int ty = tid >> 4, tx = tid & 15;
    const int lm = tid >> 2;          // 0..63 row for loads
    const int lk = (tid & 3) << 2;    // k offset (float4)
    float acc[4][4] = {{0.f}};
    for (int k0 = 0; k0 < 1024; k0 += 16) {
        float4 a4 = *(const float4*)&x[(m0 + lm) * 1024 + k0 + lk];
        float4 b4 = *(const float4*)&W[(n0 + lm) * 1024 + k0 + lk];
        __syncthreads();
        As[lk + 0][lm] = a4.x; As[lk + 1][lm] = a4.y;
        As[lk + 2][lm] = a4.z; As[lk + 3][lm] = a4.w;
        Bs[lk + 0][lm] = b4.x; Bs[lk + 1][lm] = b4.y;
        Bs[lk + 2][lm] = b4.z; Bs[lk + 3][lm] = b4.w;
        __syncthreads();
        #pragma unroll
        for (int kk = 0; kk < 16; ++kk) {
            float4 a = *(const float4*)&As[kk][ty * 4];
            float4 b = *(const float4*)&Bs[kk][tx * 4];
            float av[4] = {a.x, a.y, a.z, a.w};
            float bv[4] = {b.x, b.y, b.z, b.w};
            #pragma unroll
            for (int i = 0; i < 4; ++i)
                #pragma unroll
                for (int j = 0; j < 4; ++j)
                    acc[i][j] += av[i] * bv[j];
        }
    }
    #pragma unroll
    for (int i = 0; i < 4; ++i) {
        const int m = m0 + ty * 4 + i;
        const int bb = m >> 11, t = m & 2047;
        #pragma unroll
        for (int j = 0; j < 4; ++j) {
            const int n = n0 + tx * 4 + j;
            float val = acc[i][j] + bias[n];
            const int part = n >> 10, c = n & 1023;
            const int h = c >> 6, d = c & 63;
            if (part == 0) val *= 0.125f;   // fold softmax scale into q
            u16* dst = (part == 0) ? q : (part == 1) ? k : v;
            dst[(((bb << 4) + h) * T_ + t) * DH + d] = f2bf(val);
        }
    }
}

// ---------------- MFMA flash attention ----------------
// Block: 4 waves, each owns 16 q-rows of a 64-row q-tile. KV tile = 64.
// mfma_f32_16x16x32_bf16 layouts (guide m89/m91, verified):
//   a[j] = A[lane&15][(lane>>4)*8 + j]
//   b[j] = B[(lane>>4)*8 + j][lane&15]
//   d[r] = D[(lane>>4)*4 + r][lane&15]
__global__ __launch_bounds__(256) void flash_attn(
    const u16* __restrict__ Q, const u16* __restrict__ K,
    const u16* __restrict__ V, u16* __restrict__ Y)
{
    __shared__ __align__(16) char KsB[64 * 128];      // K tile row-major [k][d], XOR-swizzled
    __shared__ __align__(16) char VtB[64 * 128];      // V tile transposed [d][k], XOR-swizzled
    __shared__ __align__(16) char PsB[4][16 * 128];   // per-wave P [qrow16][k64], XOR-swizzled

    const int qt = blockIdx.x, bh = blockIdx.y;
    const int tid = threadIdx.x;
    const int w  = tid >> 6;        // wave 0..3
    const int l  = tid & 63;
    const int li = l & 15, lg = l >> 4;
    const u16* Qb = Q + bh * (T_ * DH);
    const u16* Kb = K + bh * (T_ * DH);
    const u16* Vb = V + bh * (T_ * DH);

    // Q a-frags in registers (Q already pre-scaled by 0.125)
    bf16x8 qa[2];
    {
        const int qrow = qt * 64 + w * 16 + li;
        qa[0] = *(const bf16x8*)(Qb + qrow * 64 + 0  + lg * 8);
        qa[1] = *(const bf16x8*)(Qb + qrow * 64 + 32 + lg * 8);
    }
    f32x4 o[4];
    #pragma unroll
    for (int nb = 0; nb < 4; ++nb) o[nb] = (f32x4){0.f, 0.f, 0.f, 0.f};
    float m_r[4], l_r[4];
    #pragma unroll
    for (int r = 0; r < 4; ++r) { m_r[r] = -INFINITY; l_r[r] = 0.f; }

    const int srow = tid >> 2;      // staging row 0..63
    const int sseg = tid & 3;       // staging 16B segment

    char* Pw = PsB[w];

    for (int kt = 0; kt <= qt; ++kt) {
        // ---- issue global loads (K and V tile, 16B x2 per thread each) ----
        const uint4* gk = (const uint4*)(Kb + (kt * 64 + srow) * 64);
        const uint4* gv = (const uint4*)(Vb + (kt * 64 + srow) * 64);
        uint4 k0 = gk[sseg], k1 = gk[sseg + 4];
        uint4 v0 = gv[sseg], v1 = gv[sseg + 4];
        __syncthreads();            // previous tile fully consumed
        // K: row-major, swizzle byte ^= (row&7)<<4
        *(uint4*)&KsB[srow * 128 + ((sseg * 16)       ^ ((srow & 7) << 4))] = k0;
        *(uint4*)&KsB[srow * 128 + (((sseg + 4) * 16) ^ ((srow & 7) << 4))] = k1;
        // V transposed: Vt[d][k], swizzle key mixes seg so staging avoids self-conflict
        {
            const u32 vv[8] = {v0.x, v0.y, v0.z, v0.w, v1.x, v1.y, v1.z, v1.w};
            #pragma unroll
            for (int h = 0; h < 2; ++h)
                #pragma unroll
                for (int jj = 0; jj < 4; ++jj) {
                    u32 u = vv[h * 4 + jj];
                    int d0 = (sseg + h * 4) * 8 + jj * 2;
                    int d1 = d0 + 1;
                    int key0 = ((d0 + (d0 >> 3)) & 7) << 4;
                    int key1 = ((d1 + (d1 >> 3)) & 7) << 4;
                    *(u16*)&VtB[d0 * 128 + ((srow * 2) ^ key0)] = (u16)(u & 0xffffu);
                    *(u16*)&VtB[d1 * 128 + ((srow * 2) ^ key1)] = (u16)(u >> 16);
                }
        }
        __syncthreads();            // tiles ready

        // ---- S = Q . K^T : s[f] covers kcols f*16..f*16+15 ----
        f32x4 s[4];
        #pragma unroll
        for (int f = 0; f < 4; ++f) {
            s[f] = (f32x4){0.f, 0.f, 0.f, 0.f};
            #pragma unroll
            for (int c = 0; c < 2; ++c) {
                const int row = f * 16 + li;
                bf16x8 kb = *(const bf16x8*)&KsB[row * 128 + ((c * 64 + lg * 16) ^ ((li & 7) << 4))];
                s[f] = __builtin_amdgcn_mfma_f32_16x16x32_bf16(qa[c], kb, s[f], 0, 0, 0);
            }
        }
        // ---- causal mask on diagonal tile ----
        if (kt == qt) {
            #pragma unroll
            for (int f = 0; f < 4; ++f)
                #pragma unroll
                for (int r = 0; r < 4; ++r)
                    if (f * 16 + li > w * 16 + lg * 4 + r) s[f][r] = -INFINITY;
        }
        // ---- online softmax (rows lg*4+r, reduce over li via shfl) ----
        #pragma unroll
        for (int r = 0; r < 4; ++r) {
            float tm = fmaxf(fmaxf(s[0][r], s[1][r]), fmaxf(s[2][r], s[3][r]));
            tm = fmaxf(tm, __shfl_xor(tm, 1));
            tm = fmaxf(tm, __shfl_xor(tm, 2));
            tm = fmaxf(tm, __shfl_xor(tm, 4));
            tm = fmaxf(tm, __shfl_xor(tm, 8));
            const float mnew = fmaxf(m_r[r], tm);
            const float corr = __expf(m_r[r] - mnew);
            m_r[r] = mnew;
            float ps = 0.f;
            #pragma unroll
            for (int f = 0; f < 4; ++f) {
                float p = __expf(s[f][r] - mnew);
                s[f][r] = p;
                ps += p;
            }
            ps += __shfl_xor(ps, 1);
            ps += __shfl_xor(ps, 2);
            ps += __shfl_xor(ps, 4);
            ps += __shfl_xor(ps, 8);
            l_r[r] = l_r[r] * corr + ps;
            #pragma unroll
            for (int nb = 0; nb < 4; ++nb) o[nb][r] *= corr;
        }
        // ---- P -> per-wave LDS (bf16, swizzled); no cross-wave sync needed ----
        #pragma unroll
        for (int f = 0; f < 4; ++f)
            #pragma unroll
            for (int r = 0; r < 4; ++r) {
                const int row = lg * 4 + r;
                const int colb = (f * 16 + li) * 2;
                *(u16*)&Pw[row * 128 + (colb ^ ((row & 7) << 4))] = f2bf(s[f][r]);
            }
        // ---- O += P @ V ----
        #pragma unroll
        for (int c = 0; c < 2; ++c) {
            bf16x8 pa = *(const bf16x8*)&Pw[li * 128 + ((c * 64 + lg * 16) ^ ((li & 7) << 4))];
            #pragma unroll
            for (int nb = 0; nb < 4; ++nb) {
                const int vrow = nb * 16 + li;
                const int key = ((vrow + (vrow >> 3)) & 7) << 4;
                bf16x8 vb = *(const bf16x8*)&VtB[vrow * 128 + ((c * 64 + lg * 16) ^ key)];
                o[nb] = __builtin_amdgcn_mfma_f32_16x16x32_bf16(pa, vb, o[nb], 0, 0, 0);
            }
        }
    }

    // ---- epilogue: divide by l, write Y bf16 ----
    const int qrow0 = qt * 64 + w * 16;
    #pragma unroll
    for (int r = 0; r < 4; ++r) {
        const float inv = 1.0f / l_r[r];
        const int row = qrow0 + lg * 4 + r;
        u16* yp = Y + bh * (T_ * DH) + row * 64 + li;
        #pragma unroll
        for (int nb = 0; nb < 4; ++nb)
            yp[nb * 16] = f2bf(o[nb][r] * inv);
    }
}

// ---------------- output projection: out = Y @ W_proj^T + b_proj ----------------
__global__ __launch_bounds__(256) void proj_gemm(
    const u16* __restrict__ Y, const float* __restrict__ W,
    const float* __restrict__ bias, float* __restrict__ out)
{
    __shared__ float As[16][68];
    __shared__ float Bs[16][68];
    const int tid = threadIdx.x;
    const int m0 = blockIdx.y * 64;
    const int n0 = blockIdx.x * 64;
    const int ty = tid >> 4, tx = tid & 15;
    const int lm = tid >> 2;
    const int lk = (tid & 3) << 2;
    const int m = m0 + lm;
    const int bb = m >> 11, t = m & 2047;
    float acc[4][4] = {{0.f}};
    for (int k0 = 0; k0 < 1024; k0 += 16) {
        const int kcol = k0 + lk;
        const int h = kcol >> 6, dd = kcol & 63;
        uint2 u = *(const uint2*)&Y[(((bb << 4) + h) * T_ + t) * DH + dd];
        float4 b4 = *(const float4*)&W[(n0 + lm) * 1024 + kcol];
        __syncthreads();
        As[lk + 0][lm] = bflo(u.x); As[lk + 1][lm] = bfhi(u.x);
        As[lk + 2][lm] = bflo(u.y); As[lk + 3][lm] = bfhi(u.y);
        Bs[lk + 0][lm] = b4.x; Bs[lk + 1][lm] = b4.y;
        Bs[lk + 2][lm] = b4.z; Bs[lk + 3][lm] = b4.w;
        __syncthreads();
        #pragma unroll
        for (int kk = 0; kk < 16; ++kk) {
            float4 a = *(const float4*)&As[kk][ty * 4];
            float4 b = *(const float4*)&Bs[kk][tx * 4];
            float av[4] = {a.x, a.y, a.z, a.w};
            float bv[4] = {b.x, b.y, b.z, b.w};
            #pragma unroll
            for (int i = 0; i < 4; ++i)
                #pragma unroll
                for (int j = 0; j < 4; ++j)
                    acc[i][j] += av[i] * bv[j];
        }
    }
    #pragma unroll
    for (int i = 0; i < 4; ++i) {
        const int mm = m0 + ty * 4 + i;
        #pragma unroll
        for (int j = 0; j < 4; ++j) {
            const int n = n0 + tx * 4 + j;
            out[mm * 1024 + n] = acc[i][j] + bias[n];
        }
    }
}

extern "C" void kernel_launch(void* const* d_in, const int* in_sizes, int n_in,
                              void* d_out, int out_size, void* d_ws, size_t ws_size,
                              hipStream_t stream) {
    const float* x      = (const float*)d_in[0];
    const float* W_attn = (const float*)d_in[1];
    const float* b_attn = (const float*)d_in[2];
    const float* W_proj = (const float*)d_in[3];
    const float* b_proj = (const float*)d_in[4];
    float* out = (float*)d_out;

    u16* q = (u16*)d_ws;       // each NQ elems (8 MB)
    u16* k = q + NQ;
    u16* v = k + NQ;
    u16* y = v + NQ;

    qkv_gemm<<<dim3(48, 64), 256, 0, stream>>>(x, W_attn, b_attn, q, k, v);
    flash_attn<<<dim3(32, 32), 256, 0, stream>>>(q, k, v, y);
    proj_gemm<<<dim3(16, 64), 256, 0, stream>>>(y, W_proj, b_proj, out);
}

// Round 3
// 205.664 us; speedup vs baseline: 6.5051x; 2.8158x over previous
//
#include <hip/hip_runtime.h>

typedef unsigned int u32;
typedef unsigned short u16;
typedef __attribute__((ext_vector_type(8))) short bf16x8;
typedef __attribute__((ext_vector_type(4))) float f32x4;

#define T_ 2048
#define HEADS 16
#define DH 64
#define NQ (2 * HEADS * T_ * DH)  // 4194304 elems per tensor

__device__ __forceinline__ float bflo(u32 u) {
    union { u32 uu; float f; } x; x.uu = u << 16; return x.f;
}
__device__ __forceinline__ float bfhi(u32 u) {
    union { u32 uu; float f; } x; x.uu = u & 0xffff0000u; return x.f;
}
__device__ __forceinline__ u16 f2bf(float f) {
    union { float f; u32 u; } x; x.f = f;
    return (u16)((x.u + 0x7fffu + ((x.u >> 16) & 1u)) >> 16);
}
// packed f32x2 -> bf16x2 (RNE), single HW instruction
__device__ __forceinline__ u32 pkbf(float lo, float hi) {
    u32 r;
    asm("v_cvt_pk_bf16_f32 %0, %1, %2" : "=v"(r) : "v"(lo), "v"(hi));
    return r;
}

// ================= MFMA GEMM (B^T form): C[m][n] = sum_k A[m][k]*B[n][k] =================
// 128x128 tile, BK=64, 4 waves (2x2), 4x4 frags of mfma_f32_16x16x32_bf16.
// A: fp32 (EPI==0, x) or bf16 (EPI==1, Y). B: fp32, converted inline via v_cvt_pk_bf16_f32.
// LDS tiles [128][64] bf16, 16B-seg XOR swizzle: phys_seg = seg ^ (row&7)  (conflict-free
// for both the staging ds_write_b128 and the fragment ds_read_b128).
// EPI 0: qkv epilogue (scatter bf16 to q/k/v [B,H,T,D], q scaled by 0.125)
// EPI 1: proj epilogue (fp32 out + bias)
template<int EPI>
__global__ __launch_bounds__(256, 2) void gemm_bt(
    const void* __restrict__ Aop, const float* __restrict__ B,
    const float* __restrict__ bias,
    u16* __restrict__ q, u16* __restrict__ k, u16* __restrict__ v,
    float* __restrict__ outF)
{
    constexpr bool ABF16 = (EPI == 1);
    constexpr int K = 1024;
    __shared__ __align__(16) char AsB[16384];
    __shared__ __align__(16) char BsB[16384];
    const int tid = threadIdx.x;
    const int l = tid & 63, li = l & 15, lg = l >> 4;
    const int w = tid >> 6, wm = w >> 1, wn = w & 1;
    const int m0 = blockIdx.y * 128, n0 = blockIdx.x * 128;

    int sr[4], sp[4];
    #pragma unroll
    for (int j = 0; j < 4; ++j) { const int s = tid + j * 256; sr[j] = s >> 3; sp[j] = s & 7; }

    f32x4 acc[4][4];
    #pragma unroll
    for (int i = 0; i < 4; ++i)
        #pragma unroll
        for (int j = 0; j < 4; ++j) acc[i][j] = (f32x4){0.f, 0.f, 0.f, 0.f};

    const float* Af = (const float*)Aop;
    const u16*   Ah = (const u16*)Aop;

    float4 ar[4][2];
    uint4  arh[4];
    float4 br[4][2];

    // ---- prefetch tile 0 ----
    #pragma unroll
    for (int j = 0; j < 4; ++j) {
        if constexpr (ABF16) {
            arh[j] = *(const uint4*)(Ah + (m0 + sr[j]) * K + sp[j] * 8);
        } else {
            const float* p = Af + (m0 + sr[j]) * K + sp[j] * 8;
            ar[j][0] = *(const float4*)p; ar[j][1] = *(const float4*)(p + 4);
        }
        const float* pb = B + (n0 + sr[j]) * K + sp[j] * 8;
        br[j][0] = *(const float4*)pb; br[j][1] = *(const float4*)(pb + 4);
    }

    for (int kt = 0; kt < K; kt += 64) {
        __syncthreads();   // previous tile fully consumed
        // ---- cvt + swizzled LDS store of the prefetched tile ----
        #pragma unroll
        for (int j = 0; j < 4; ++j) {
            const int off = sr[j] * 128 + ((sp[j] ^ (sr[j] & 7)) << 4);
            if constexpr (ABF16) {
                *(uint4*)&AsB[off] = arh[j];
            } else {
                uint4 t;
                t.x = pkbf(ar[j][0].x, ar[j][0].y); t.y = pkbf(ar[j][0].z, ar[j][0].w);
                t.z = pkbf(ar[j][1].x, ar[j][1].y); t.w = pkbf(ar[j][1].z, ar[j][1].w);
                *(uint4*)&AsB[off] = t;
            }
            uint4 tb;
            tb.x = pkbf(br[j][0].x, br[j][0].y); tb.y = pkbf(br[j][0].z, br[j][0].w);
            tb.z = pkbf(br[j][1].x, br[j][1].y); tb.w = pkbf(br[j][1].z, br[j][1].w);
            *(uint4*)&BsB[off] = tb;
        }
        __syncthreads();   // tile ready
        // ---- issue next tile's global loads early (hide HBM under MFMA) ----
        if (kt + 64 < K) {
            const int kn = kt + 64;
            #pragma unroll
            for (int j = 0; j < 4; ++j) {
                if constexpr (ABF16) {
                    arh[j] = *(const uint4*)(Ah + (m0 + sr[j]) * K + kn + sp[j] * 8);
                } else {
                    const float* p = Af + (m0 + sr[j]) * K + kn + sp[j] * 8;
                    ar[j][0] = *(const float4*)p; ar[j][1] = *(const float4*)(p + 4);
                }
                const float* pb = B + (n0 + sr[j]) * K + kn + sp[j] * 8;
                br[j][0] = *(const float4*)pb; br[j][1] = *(const float4*)(pb + 4);
            }
        }
        // ---- compute ----
        #pragma unroll
        for (int kc = 0; kc < 2; ++kc) {
            const int key = ((kc * 4 + lg) ^ (li & 7)) << 4;
            bf16x8 a[4], b[4];
            #pragma unroll
            for (int f = 0; f < 4; ++f)
                a[f] = *(const bf16x8*)&AsB[(wm * 64 + f * 16 + li) * 128 + key];
            #pragma unroll
            for (int f = 0; f < 4; ++f)
                b[f] = *(const bf16x8*)&BsB[(wn * 64 + f * 16 + li) * 128 + key];
            #pragma unroll
            for (int mi = 0; mi < 4; ++mi)
                #pragma unroll
                for (int ni = 0; ni < 4; ++ni)
                    acc[mi][ni] = __builtin_amdgcn_mfma_f32_16x16x32_bf16(a[mi], b[ni], acc[mi][ni], 0, 0, 0);
        }
    }

    // ---- epilogue: d[r] = D[lg*4+r][li] ----
    const int mb = m0 + wm * 64;
    const int nb0 = n0 + wn * 64;
    if constexpr (EPI == 0) {
        const int part = n0 >> 10;          // block never crosses a 1024 boundary
        u16* dst = (part == 0) ? q : (part == 1) ? k : v;
        const float scl = (part == 0) ? 0.125f : 1.0f;
        #pragma unroll
        for (int mi = 0; mi < 4; ++mi)
            #pragma unroll
            for (int r = 0; r < 4; ++r) {
                const int m = mb + mi * 16 + lg * 4 + r;
                const int bb = m >> 11, t = m & 2047;
                #pragma unroll
                for (int ni = 0; ni < 4; ++ni) {
                    const int n = nb0 + ni * 16 + li;
                    const int c = n & 1023;
                    const int h = c >> 6, d = c & 63;
                    const float val = (acc[mi][ni][r] + bias[n]) * scl;
                    dst[(((bb << 4) + h) * T_ + t) * DH + d] = f2bf(val);
                }
            }
    } else {
        #pragma unroll
        for (int mi = 0; mi < 4; ++mi)
            #pragma unroll
            for (int r = 0; r < 4; ++r) {
                const int m = mb + mi * 16 + lg * 4 + r;
                #pragma unroll
                for (int ni = 0; ni < 4; ++ni) {
                    const int n = nb0 + ni * 16 + li;
                    outF[m * 1024 + n] = acc[mi][ni][r] + bias[n];
                }
            }
    }
}

// ---------------- MFMA flash attention (round-1, Y layout -> [B,T,C]) ----------------
__global__ __launch_bounds__(256) void flash_attn(
    const u16* __restrict__ Q, const u16* __restrict__ K,
    const u16* __restrict__ V, u16* __restrict__ Y)
{
    __shared__ __align__(16) char KsB[64 * 128];      // K tile row-major [k][d], XOR-swizzled
    __shared__ __align__(16) char VtB[64 * 128];      // V tile transposed [d][k], XOR-swizzled
    __shared__ __align__(16) char PsB[4][16 * 128];   // per-wave P [qrow16][k64], XOR-swizzled

    const int qt = blockIdx.x, bh = blockIdx.y;
    const int tid = threadIdx.x;
    const int w  = tid >> 6;
    const int l  = tid & 63;
    const int li = l & 15, lg = l >> 4;
    const u16* Qb = Q + bh * (T_ * DH);
    const u16* Kb = K + bh * (T_ * DH);
    const u16* Vb = V + bh * (T_ * DH);

    bf16x8 qa[2];
    {
        const int qrow = qt * 64 + w * 16 + li;
        qa[0] = *(const bf16x8*)(Qb + qrow * 64 + 0  + lg * 8);
        qa[1] = *(const bf16x8*)(Qb + qrow * 64 + 32 + lg * 8);
    }
    f32x4 o[4];
    #pragma unroll
    for (int nb = 0; nb < 4; ++nb) o[nb] = (f32x4){0.f, 0.f, 0.f, 0.f};
    float m_r[4], l_r[4];
    #pragma unroll
    for (int r = 0; r < 4; ++r) { m_r[r] = -INFINITY; l_r[r] = 0.f; }

    const int srow = tid >> 2;
    const int sseg = tid & 3;
    char* Pw = PsB[w];

    for (int kt = 0; kt <= qt; ++kt) {
        const uint4* gk = (const uint4*)(Kb + (kt * 64 + srow) * 64);
        const uint4* gv = (const uint4*)(Vb + (kt * 64 + srow) * 64);
        uint4 k0 = gk[sseg], k1 = gk[sseg + 4];
        uint4 v0 = gv[sseg], v1 = gv[sseg + 4];
        __syncthreads();
        *(uint4*)&KsB[srow * 128 + ((sseg * 16)       ^ ((srow & 7) << 4))] = k0;
        *(uint4*)&KsB[srow * 128 + (((sseg + 4) * 16) ^ ((srow & 7) << 4))] = k1;
        {
            const u32 vv[8] = {v0.x, v0.y, v0.z, v0.w, v1.x, v1.y, v1.z, v1.w};
            #pragma unroll
            for (int h = 0; h < 2; ++h)
                #pragma unroll
                for (int jj = 0; jj < 4; ++jj) {
                    u32 u = vv[h * 4 + jj];
                    int d0 = (sseg + h * 4) * 8 + jj * 2;
                    int d1 = d0 + 1;
                    int key0 = ((d0 + (d0 >> 3)) & 7) << 4;
                    int key1 = ((d1 + (d1 >> 3)) & 7) << 4;
                    *(u16*)&VtB[d0 * 128 + ((srow * 2) ^ key0)] = (u16)(u & 0xffffu);
                    *(u16*)&VtB[d1 * 128 + ((srow * 2) ^ key1)] = (u16)(u >> 16);
                }
        }
        __syncthreads();

        f32x4 s[4];
        #pragma unroll
        for (int f = 0; f < 4; ++f) {
            s[f] = (f32x4){0.f, 0.f, 0.f, 0.f};
            #pragma unroll
            for (int c = 0; c < 2; ++c) {
                const int row = f * 16 + li;
                bf16x8 kb = *(const bf16x8*)&KsB[row * 128 + ((c * 64 + lg * 16) ^ ((li & 7) << 4))];
                s[f] = __builtin_amdgcn_mfma_f32_16x16x32_bf16(qa[c], kb, s[f], 0, 0, 0);
            }
        }
        if (kt == qt) {
            #pragma unroll
            for (int f = 0; f < 4; ++f)
                #pragma unroll
                for (int r = 0; r < 4; ++r)
                    if (f * 16 + li > w * 16 + lg * 4 + r) s[f][r] = -INFINITY;
        }
        #pragma unroll
        for (int r = 0; r < 4; ++r) {
            float tm = fmaxf(fmaxf(s[0][r], s[1][r]), fmaxf(s[2][r], s[3][r]));
            tm = fmaxf(tm, __shfl_xor(tm, 1));
            tm = fmaxf(tm, __shfl_xor(tm, 2));
            tm = fmaxf(tm, __shfl_xor(tm, 4));
            tm = fmaxf(tm, __shfl_xor(tm, 8));
            const float mnew = fmaxf(m_r[r], tm);
            const float corr = __expf(m_r[r] - mnew);
            m_r[r] = mnew;
            float ps = 0.f;
            #pragma unroll
            for (int f = 0; f < 4; ++f) {
                float p = __expf(s[f][r] - mnew);
                s[f][r] = p;
                ps += p;
            }
            ps += __shfl_xor(ps, 1);
            ps += __shfl_xor(ps, 2);
            ps += __shfl_xor(ps, 4);
            ps += __shfl_xor(ps, 8);
            l_r[r] = l_r[r] * corr + ps;
            #pragma unroll
            for (int nb = 0; nb < 4; ++nb) o[nb][r] *= corr;
        }
        #pragma unroll
        for (int f = 0; f < 4; ++f)
            #pragma unroll
            for (int r = 0; r < 4; ++r) {
                const int row = lg * 4 + r;
                const int colb = (f * 16 + li) * 2;
                *(u16*)&Pw[row * 128 + (colb ^ ((row & 7) << 4))] = f2bf(s[f][r]);
            }
        #pragma unroll
        for (int c = 0; c < 2; ++c) {
            bf16x8 pa = *(const bf16x8*)&Pw[li * 128 + ((c * 64 + lg * 16) ^ ((li & 7) << 4))];
            #pragma unroll
            for (int nb = 0; nb < 4; ++nb) {
                const int vrow = nb * 16 + li;
                const int key = ((vrow + (vrow >> 3)) & 7) << 4;
                bf16x8 vb = *(const bf16x8*)&VtB[vrow * 128 + ((c * 64 + lg * 16) ^ key)];
                o[nb] = __builtin_amdgcn_mfma_f32_16x16x32_bf16(pa, vb, o[nb], 0, 0, 0);
            }
        }
    }

    // epilogue: Y in [B,T,C] layout (C index = h*64 + d) for the proj GEMM
    const int b = bh >> 4, h = bh & 15;
    const int qrow0 = qt * 64 + w * 16;
    #pragma unroll
    for (int r = 0; r < 4; ++r) {
        const float inv = 1.0f / l_r[r];
        const int row = qrow0 + lg * 4 + r;
        u16* yp = Y + ((b * T_ + row) * 1024) + h * DH + li;
        #pragma unroll
        for (int nb = 0; nb < 4; ++nb)
            yp[nb * 16] = f2bf(o[nb][r] * inv);
    }
}

extern "C" void kernel_launch(void* const* d_in, const int* in_sizes, int n_in,
                              void* d_out, int out_size, void* d_ws, size_t ws_size,
                              hipStream_t stream) {
    const float* x      = (const float*)d_in[0];
    const float* W_attn = (const float*)d_in[1];
    const float* b_attn = (const float*)d_in[2];
    const float* W_proj = (const float*)d_in[3];
    const float* b_proj = (const float*)d_in[4];
    float* out = (float*)d_out;

    u16* q = (u16*)d_ws;       // each NQ elems (8 MB)
    u16* k = q + NQ;
    u16* v = k + NQ;
    u16* y = v + NQ;           // [B,T,C] bf16

    gemm_bt<0><<<dim3(24, 32), 256, 0, stream>>>(x, W_attn, b_attn, q, k, v, nullptr);
    flash_attn<<<dim3(32, 32), 256, 0, stream>>>(q, k, v, y);
    gemm_bt<1><<<dim3(8, 32), 256, 0, stream>>>(y, W_proj, b_proj, nullptr, nullptr, nullptr, out);
}

// Round 4
// 156.324 us; speedup vs baseline: 8.5583x; 1.3156x over previous
//
#include <hip/hip_runtime.h>

typedef unsigned int u32;
typedef unsigned short u16;
typedef __attribute__((ext_vector_type(8))) short bf16x8;
typedef __attribute__((ext_vector_type(4))) float f32x4;

#define T_ 2048
#define HEADS 16
#define DH 64
#define NQ (2 * HEADS * T_ * DH)  // 4194304 elems per tensor

__device__ __forceinline__ float bflo(u32 u) {
    union { u32 uu; float f; } x; x.uu = u << 16; return x.f;
}
__device__ __forceinline__ float bfhi(u32 u) {
    union { u32 uu; float f; } x; x.uu = u & 0xffff0000u; return x.f;
}
__device__ __forceinline__ u16 f2bf(float f) {
    union { float f; u32 u; } x; x.f = f;
    return (u16)((x.u + 0x7fffu + ((x.u >> 16) & 1u)) >> 16);
}
// packed f32x2 -> bf16x2 (RNE), single HW instruction
__device__ __forceinline__ u32 pkbf(float lo, float hi) {
    u32 r;
    asm("v_cvt_pk_bf16_f32 %0, %1, %2" : "=v"(r) : "v"(lo), "v"(hi));
    return r;
}

// ================= MFMA GEMM (B^T form): C[m][n] = sum_k A[m][k]*B[n][k] =================
// (unchanged from round 2 — working)
template<int EPI>
__global__ __launch_bounds__(256, 2) void gemm_bt(
    const void* __restrict__ Aop, const float* __restrict__ B,
    const float* __restrict__ bias,
    u16* __restrict__ q, u16* __restrict__ k, u16* __restrict__ v,
    float* __restrict__ outF)
{
    constexpr bool ABF16 = (EPI == 1);
    constexpr int K = 1024;
    __shared__ __align__(16) char AsB[16384];
    __shared__ __align__(16) char BsB[16384];
    const int tid = threadIdx.x;
    const int l = tid & 63, li = l & 15, lg = l >> 4;
    const int w = tid >> 6, wm = w >> 1, wn = w & 1;
    const int m0 = blockIdx.y * 128, n0 = blockIdx.x * 128;

    int sr[4], sp[4];
    #pragma unroll
    for (int j = 0; j < 4; ++j) { const int s = tid + j * 256; sr[j] = s >> 3; sp[j] = s & 7; }

    f32x4 acc[4][4];
    #pragma unroll
    for (int i = 0; i < 4; ++i)
        #pragma unroll
        for (int j = 0; j < 4; ++j) acc[i][j] = (f32x4){0.f, 0.f, 0.f, 0.f};

    const float* Af = (const float*)Aop;
    const u16*   Ah = (const u16*)Aop;

    float4 ar[4][2];
    uint4  arh[4];
    float4 br[4][2];

    #pragma unroll
    for (int j = 0; j < 4; ++j) {
        if constexpr (ABF16) {
            arh[j] = *(const uint4*)(Ah + (m0 + sr[j]) * K + sp[j] * 8);
        } else {
            const float* p = Af + (m0 + sr[j]) * K + sp[j] * 8;
            ar[j][0] = *(const float4*)p; ar[j][1] = *(const float4*)(p + 4);
        }
        const float* pb = B + (n0 + sr[j]) * K + sp[j] * 8;
        br[j][0] = *(const float4*)pb; br[j][1] = *(const float4*)(pb + 4);
    }

    for (int kt = 0; kt < K; kt += 64) {
        __syncthreads();
        #pragma unroll
        for (int j = 0; j < 4; ++j) {
            const int off = sr[j] * 128 + ((sp[j] ^ (sr[j] & 7)) << 4);
            if constexpr (ABF16) {
                *(uint4*)&AsB[off] = arh[j];
            } else {
                uint4 t;
                t.x = pkbf(ar[j][0].x, ar[j][0].y); t.y = pkbf(ar[j][0].z, ar[j][0].w);
                t.z = pkbf(ar[j][1].x, ar[j][1].y); t.w = pkbf(ar[j][1].z, ar[j][1].w);
                *(uint4*)&AsB[off] = t;
            }
            uint4 tb;
            tb.x = pkbf(br[j][0].x, br[j][0].y); tb.y = pkbf(br[j][0].z, br[j][0].w);
            tb.z = pkbf(br[j][1].x, br[j][1].y); tb.w = pkbf(br[j][1].z, br[j][1].w);
            *(uint4*)&BsB[off] = tb;
        }
        __syncthreads();
        if (kt + 64 < K) {
            const int kn = kt + 64;
            #pragma unroll
            for (int j = 0; j < 4; ++j) {
                if constexpr (ABF16) {
                    arh[j] = *(const uint4*)(Ah + (m0 + sr[j]) * K + kn + sp[j] * 8);
                } else {
                    const float* p = Af + (m0 + sr[j]) * K + kn + sp[j] * 8;
                    ar[j][0] = *(const float4*)p; ar[j][1] = *(const float4*)(p + 4);
                }
                const float* pb = B + (n0 + sr[j]) * K + kn + sp[j] * 8;
                br[j][0] = *(const float4*)pb; br[j][1] = *(const float4*)(pb + 4);
            }
        }
        #pragma unroll
        for (int kc = 0; kc < 2; ++kc) {
            const int key = ((kc * 4 + lg) ^ (li & 7)) << 4;
            bf16x8 a[4], b[4];
            #pragma unroll
            for (int f = 0; f < 4; ++f)
                a[f] = *(const bf16x8*)&AsB[(wm * 64 + f * 16 + li) * 128 + key];
            #pragma unroll
            for (int f = 0; f < 4; ++f)
                b[f] = *(const bf16x8*)&BsB[(wn * 64 + f * 16 + li) * 128 + key];
            #pragma unroll
            for (int mi = 0; mi < 4; ++mi)
                #pragma unroll
                for (int ni = 0; ni < 4; ++ni)
                    acc[mi][ni] = __builtin_amdgcn_mfma_f32_16x16x32_bf16(a[mi], b[ni], acc[mi][ni], 0, 0, 0);
        }
    }

    const int mb = m0 + wm * 64;
    const int nb0 = n0 + wn * 64;
    if constexpr (EPI == 0) {
        const int part = n0 >> 10;
        u16* dst = (part == 0) ? q : (part == 1) ? k : v;
        const float scl = (part == 0) ? 0.125f : 1.0f;
        #pragma unroll
        for (int mi = 0; mi < 4; ++mi)
            #pragma unroll
            for (int r = 0; r < 4; ++r) {
                const int m = mb + mi * 16 + lg * 4 + r;
                const int bb = m >> 11, t = m & 2047;
                #pragma unroll
                for (int ni = 0; ni < 4; ++ni) {
                    const int n = nb0 + ni * 16 + li;
                    const int c = n & 1023;
                    const int h = c >> 6, d = c & 63;
                    const float val = (acc[mi][ni][r] + bias[n]) * scl;
                    dst[(((bb << 4) + h) * T_ + t) * DH + d] = f2bf(val);
                }
            }
    } else {
        #pragma unroll
        for (int mi = 0; mi < 4; ++mi)
            #pragma unroll
            for (int r = 0; r < 4; ++r) {
                const int m = mb + mi * 16 + lg * 4 + r;
                #pragma unroll
                for (int ni = 0; ni < 4; ++ni) {
                    const int n = nb0 + ni * 16 + li;
                    outF[m * 1024 + n] = acc[mi][ni][r] + bias[n];
                }
            }
    }
}

// ---------------- MFMA flash attention, balanced + double-buffered ----------------
// Grid (16, 32): block x handles q-tiles {x, 31-x} for bh = blockIdx.y -> 33 KV-tiles/block.
// LDS: K dbuf 2x8KB, Vt dbuf 2x8KB, P 4x2KB = 40KB. One __syncthreads per KV tile.
__global__ __launch_bounds__(256) void flash_attn(
    const u16* __restrict__ Q, const u16* __restrict__ K,
    const u16* __restrict__ V, u16* __restrict__ Y)
{
    __shared__ __align__(16) char KsB[2][64 * 128];
    __shared__ __align__(16) char VtB[2][64 * 128];
    __shared__ __align__(16) char PsB[4][16 * 128];

    const int bh = blockIdx.y;
    const int tid = threadIdx.x;
    const int w  = tid >> 6;
    const int l  = tid & 63;
    const int li = l & 15, lg = l >> 4;
    const u16* Qb = Q + bh * (T_ * DH);
    const u16* Kb = K + bh * (T_ * DH);
    const u16* Vb = V + bh * (T_ * DH);
    const int srow = tid >> 2;
    const int sseg = tid & 3;
    char* Pw = PsB[w];

    const int b = bh >> 4, h = bh & 15;

    #pragma unroll
    for (int ph = 0; ph < 2; ++ph) {
        const int qt = ph ? (31 - (int)blockIdx.x) : (int)blockIdx.x;

        bf16x8 qa[2];
        {
            const int qrow = qt * 64 + w * 16 + li;
            qa[0] = *(const bf16x8*)(Qb + qrow * 64 + 0  + lg * 8);
            qa[1] = *(const bf16x8*)(Qb + qrow * 64 + 32 + lg * 8);
        }
        f32x4 o[4];
        #pragma unroll
        for (int nb = 0; nb < 4; ++nb) o[nb] = (f32x4){0.f, 0.f, 0.f, 0.f};
        float m_r[4], l_r[4];
        #pragma unroll
        for (int r = 0; r < 4; ++r) { m_r[r] = -INFINITY; l_r[r] = 0.f; }

        uint4 kr0, kr1, vr0, vr1;
        // ---- prologue: stage tile 0 into buf 0 ----
        {
            const uint4* gk = (const uint4*)(Kb + srow * 64);
            const uint4* gv = (const uint4*)(Vb + srow * 64);
            kr0 = gk[sseg]; kr1 = gk[sseg + 4];
            vr0 = gv[sseg]; vr1 = gv[sseg + 4];
            __syncthreads();   // prior phase's LDS fully consumed
            char* Kn = KsB[0];
            char* Vn = VtB[0];
            *(uint4*)&Kn[srow * 128 + ((sseg * 16)       ^ ((srow & 7) << 4))] = kr0;
            *(uint4*)&Kn[srow * 128 + (((sseg + 4) * 16) ^ ((srow & 7) << 4))] = kr1;
            const u32 vv[8] = {vr0.x, vr0.y, vr0.z, vr0.w, vr1.x, vr1.y, vr1.z, vr1.w};
            #pragma unroll
            for (int hh = 0; hh < 2; ++hh)
                #pragma unroll
                for (int jj = 0; jj < 4; ++jj) {
                    u32 u = vv[hh * 4 + jj];
                    int d0 = (sseg + hh * 4) * 8 + jj * 2;
                    int d1 = d0 + 1;
                    int key0 = ((d0 + (d0 >> 3)) & 7) << 4;
                    int key1 = ((d1 + (d1 >> 3)) & 7) << 4;
                    *(u16*)&Vn[d0 * 128 + ((srow * 2) ^ key0)] = (u16)(u & 0xffffu);
                    *(u16*)&Vn[d1 * 128 + ((srow * 2) ^ key1)] = (u16)(u >> 16);
                }
            __syncthreads();
        }

        for (int kt = 0; kt <= qt; ++kt) {
            const int cur = kt & 1;
            // ---- issue next tile's global loads (latency hides under S+softmax) ----
            if (kt < qt) {
                const uint4* gk = (const uint4*)(Kb + ((kt + 1) * 64 + srow) * 64);
                const uint4* gv = (const uint4*)(Vb + ((kt + 1) * 64 + srow) * 64);
                kr0 = gk[sseg]; kr1 = gk[sseg + 4];
                vr0 = gv[sseg]; vr1 = gv[sseg + 4];
            }
            // ---- S = Q.K^T ----
            const char* Kc = KsB[cur];
            f32x4 s[4];
            #pragma unroll
            for (int f = 0; f < 4; ++f) {
                s[f] = (f32x4){0.f, 0.f, 0.f, 0.f};
                #pragma unroll
                for (int c = 0; c < 2; ++c) {
                    const int row = f * 16 + li;
                    bf16x8 kb = *(const bf16x8*)&Kc[row * 128 + ((c * 64 + lg * 16) ^ ((li & 7) << 4))];
                    s[f] = __builtin_amdgcn_mfma_f32_16x16x32_bf16(qa[c], kb, s[f], 0, 0, 0);
                }
            }
            if (kt == qt) {
                #pragma unroll
                for (int f = 0; f < 4; ++f)
                    #pragma unroll
                    for (int r = 0; r < 4; ++r)
                        if (f * 16 + li > w * 16 + lg * 4 + r) s[f][r] = -INFINITY;
            }
            // ---- phased online softmax (4 independent chains interleave) ----
            float tm[4];
            #pragma unroll
            for (int r = 0; r < 4; ++r)
                tm[r] = fmaxf(fmaxf(s[0][r], s[1][r]), fmaxf(s[2][r], s[3][r]));
            #pragma unroll
            for (int st = 1; st < 16; st <<= 1)
                #pragma unroll
                for (int r = 0; r < 4; ++r)
                    tm[r] = fmaxf(tm[r], __shfl_xor(tm[r], st));
            float corr[4];
            #pragma unroll
            for (int r = 0; r < 4; ++r) {
                const float mnew = fmaxf(m_r[r], tm[r]);
                corr[r] = __expf(m_r[r] - mnew);
                m_r[r] = mnew;
            }
            float ps[4];
            #pragma unroll
            for (int r = 0; r < 4; ++r) {
                float a = 0.f;
                #pragma unroll
                for (int f = 0; f < 4; ++f) {
                    const float p = __expf(s[f][r] - m_r[r]);
                    s[f][r] = p;
                    a += p;
                }
                ps[r] = a;
            }
            #pragma unroll
            for (int st = 1; st < 16; st <<= 1)
                #pragma unroll
                for (int r = 0; r < 4; ++r)
                    ps[r] += __shfl_xor(ps[r], st);
            #pragma unroll
            for (int r = 0; r < 4; ++r) {
                l_r[r] = l_r[r] * corr[r] + ps[r];
                #pragma unroll
                for (int nb = 0; nb < 4; ++nb) o[nb][r] *= corr[r];
            }
            // ---- P -> per-wave LDS ----
            #pragma unroll
            for (int f = 0; f < 4; ++f)
                #pragma unroll
                for (int r = 0; r < 4; ++r) {
                    const int row = lg * 4 + r;
                    const int colb = (f * 16 + li) * 2;
                    *(u16*)&Pw[row * 128 + (colb ^ ((row & 7) << 4))] = f2bf(s[f][r]);
                }
            // ---- write prefetched K/V into the other buffer ----
            if (kt < qt) {
                char* Kn = KsB[cur ^ 1];
                char* Vn = VtB[cur ^ 1];
                *(uint4*)&Kn[srow * 128 + ((sseg * 16)       ^ ((srow & 7) << 4))] = kr0;
                *(uint4*)&Kn[srow * 128 + (((sseg + 4) * 16) ^ ((srow & 7) << 4))] = kr1;
                const u32 vv[8] = {vr0.x, vr0.y, vr0.z, vr0.w, vr1.x, vr1.y, vr1.z, vr1.w};
                #pragma unroll
                for (int hh = 0; hh < 2; ++hh)
                    #pragma unroll
                    for (int jj = 0; jj < 4; ++jj) {
                        u32 u = vv[hh * 4 + jj];
                        int d0 = (sseg + hh * 4) * 8 + jj * 2;
                        int d1 = d0 + 1;
                        int key0 = ((d0 + (d0 >> 3)) & 7) << 4;
                        int key1 = ((d1 + (d1 >> 3)) & 7) << 4;
                        *(u16*)&Vn[d0 * 128 + ((srow * 2) ^ key0)] = (u16)(u & 0xffffu);
                        *(u16*)&Vn[d1 * 128 + ((srow * 2) ^ key1)] = (u16)(u >> 16);
                    }
            }
            // ---- O += P @ V ----
            const char* Vc = VtB[cur];
            #pragma unroll
            for (int c = 0; c < 2; ++c) {
                bf16x8 pa = *(const bf16x8*)&Pw[li * 128 + ((c * 64 + lg * 16) ^ ((li & 7) << 4))];
                #pragma unroll
                for (int nb = 0; nb < 4; ++nb) {
                    const int vrow = nb * 16 + li;
                    const int key = ((vrow + (vrow >> 3)) & 7) << 4;
                    bf16x8 vb = *(const bf16x8*)&Vc[vrow * 128 + ((c * 64 + lg * 16) ^ key)];
                    o[nb] = __builtin_amdgcn_mfma_f32_16x16x32_bf16(pa, vb, o[nb], 0, 0, 0);
                }
            }
            __syncthreads();   // next buffer's writes visible; current buffer free
        }

        // ---- epilogue: Y in [B,T,C] ----
        const int qrow0 = qt * 64 + w * 16;
        #pragma unroll
        for (int r = 0; r < 4; ++r) {
            const float inv = 1.0f / l_r[r];
            const int row = qrow0 + lg * 4 + r;
            u16* yp = Y + ((b * T_ + row) * 1024) + h * DH + li;
            #pragma unroll
            for (int nb = 0; nb < 4; ++nb)
                yp[nb * 16] = f2bf(o[nb][r] * inv);
        }
    }
}

extern "C" void kernel_launch(void* const* d_in, const int* in_sizes, int n_in,
                              void* d_out, int out_size, void* d_ws, size_t ws_size,
                              hipStream_t stream) {
    const float* x      = (const float*)d_in[0];
    const float* W_attn = (const float*)d_in[1];
    const float* b_attn = (const float*)d_in[2];
    const float* W_proj = (const float*)d_in[3];
    const float* b_proj = (const float*)d_in[4];
    float* out = (float*)d_out;

    u16* q = (u16*)d_ws;       // each NQ elems (8 MB)
    u16* k = q + NQ;
    u16* v = k + NQ;
    u16* y = v + NQ;           // [B,T,C] bf16

    gemm_bt<0><<<dim3(24, 32), 256, 0, stream>>>(x, W_attn, b_attn, q, k, v, nullptr);
    flash_attn<<<dim3(16, 32), 256, 0, stream>>>(q, k, v, y);
    gemm_bt<1><<<dim3(8, 32), 256, 0, stream>>>(y, W_proj, b_proj, nullptr, nullptr, nullptr, out);
}

// Round 5
// 139.945 us; speedup vs baseline: 9.5600x; 1.1170x over previous
//
#include <hip/hip_runtime.h>

typedef unsigned int u32;
typedef unsigned short u16;
typedef __attribute__((ext_vector_type(8))) short bf16x8;
typedef __attribute__((ext_vector_type(4))) float f32x4;

#define T_ 2048
#define HEADS 16
#define DH 64
#define NQ (2 * HEADS * T_ * DH)  // 4194304 elems per tensor

__device__ __forceinline__ u16 f2bf(float f) {
    union { float f; u32 u; } x; x.f = f;
    return (u16)((x.u + 0x7fffu + ((x.u >> 16) & 1u)) >> 16);
}
// packed f32x2 -> bf16x2 (RNE), single HW instruction
__device__ __forceinline__ u32 pkbf(float lo, float hi) {
    u32 r;
    asm("v_cvt_pk_bf16_f32 %0, %1, %2" : "=v"(r) : "v"(lo), "v"(hi));
    return r;
}
// DPP lane-swap within 16-lane rows
template<int C>
__device__ __forceinline__ float dppf(float x) {
    union { float f; int i; } a, r;
    a.f = x;
    r.i = __builtin_amdgcn_update_dpp(a.i, a.i, C, 0xF, 0xF, false);
    return r.f;
}
// butterfly allreduce across the 16-lane group (xor1, xor2, ~xor4, ~xor8)
__device__ __forceinline__ float redmax16(float x) {
    x = fmaxf(x, dppf<0xB1>(x));    // quad_perm [1,0,3,2]  = xor 1
    x = fmaxf(x, dppf<0x4E>(x));    // quad_perm [2,3,0,1]  = xor 2
    x = fmaxf(x, dppf<0x141>(x));   // row_half_mirror (quads uniform -> xor 4)
    x = fmaxf(x, dppf<0x140>(x));   // row_mirror      (halves uniform -> xor 8)
    return x;
}
__device__ __forceinline__ float redsum16(float x) {
    x += dppf<0xB1>(x);
    x += dppf<0x4E>(x);
    x += dppf<0x141>(x);
    x += dppf<0x140>(x);
    return x;
}

// ================= MFMA GEMM (B^T form): C[m][n] = sum_k A[m][k]*B[n][k] =================
// EPI 0: qkv epilogue — q,k as [B,H,T,D] bf16 (q scaled 0.125), v TRANSPOSED as [B,H,D,T].
// EPI 1: proj epilogue (fp32 out + bias)
template<int EPI>
__global__ __launch_bounds__(256, 2) void gemm_bt(
    const void* __restrict__ Aop, const float* __restrict__ B,
    const float* __restrict__ bias,
    u16* __restrict__ q, u16* __restrict__ k, u16* __restrict__ vt,
    float* __restrict__ outF)
{
    constexpr bool ABF16 = (EPI == 1);
    constexpr int K = 1024;
    __shared__ __align__(16) char AsB[16384];
    __shared__ __align__(16) char BsB[16384];
    const int tid = threadIdx.x;
    const int l = tid & 63, li = l & 15, lg = l >> 4;
    const int w = tid >> 6, wm = w >> 1, wn = w & 1;
    const int m0 = blockIdx.y * 128, n0 = blockIdx.x * 128;

    int sr[4], sp[4];
    #pragma unroll
    for (int j = 0; j < 4; ++j) { const int s = tid + j * 256; sr[j] = s >> 3; sp[j] = s & 7; }

    f32x4 acc[4][4];
    #pragma unroll
    for (int i = 0; i < 4; ++i)
        #pragma unroll
        for (int j = 0; j < 4; ++j) acc[i][j] = (f32x4){0.f, 0.f, 0.f, 0.f};

    const float* Af = (const float*)Aop;
    const u16*   Ah = (const u16*)Aop;

    float4 ar[4][2];
    uint4  arh[4];
    float4 br[4][2];

    #pragma unroll
    for (int j = 0; j < 4; ++j) {
        if constexpr (ABF16) {
            arh[j] = *(const uint4*)(Ah + (m0 + sr[j]) * K + sp[j] * 8);
        } else {
            const float* p = Af + (m0 + sr[j]) * K + sp[j] * 8;
            ar[j][0] = *(const float4*)p; ar[j][1] = *(const float4*)(p + 4);
        }
        const float* pb = B + (n0 + sr[j]) * K + sp[j] * 8;
        br[j][0] = *(const float4*)pb; br[j][1] = *(const float4*)(pb + 4);
    }

    for (int kt = 0; kt < K; kt += 64) {
        __syncthreads();
        #pragma unroll
        for (int j = 0; j < 4; ++j) {
            const int off = sr[j] * 128 + ((sp[j] ^ (sr[j] & 7)) << 4);
            if constexpr (ABF16) {
                *(uint4*)&AsB[off] = arh[j];
            } else {
                uint4 t;
                t.x = pkbf(ar[j][0].x, ar[j][0].y); t.y = pkbf(ar[j][0].z, ar[j][0].w);
                t.z = pkbf(ar[j][1].x, ar[j][1].y); t.w = pkbf(ar[j][1].z, ar[j][1].w);
                *(uint4*)&AsB[off] = t;
            }
            uint4 tb;
            tb.x = pkbf(br[j][0].x, br[j][0].y); tb.y = pkbf(br[j][0].z, br[j][0].w);
            tb.z = pkbf(br[j][1].x, br[j][1].y); tb.w = pkbf(br[j][1].z, br[j][1].w);
            *(uint4*)&BsB[off] = tb;
        }
        __syncthreads();
        if (kt + 64 < K) {
            const int kn = kt + 64;
            #pragma unroll
            for (int j = 0; j < 4; ++j) {
                if constexpr (ABF16) {
                    arh[j] = *(const uint4*)(Ah + (m0 + sr[j]) * K + kn + sp[j] * 8);
                } else {
                    const float* p = Af + (m0 + sr[j]) * K + kn + sp[j] * 8;
                    ar[j][0] = *(const float4*)p; ar[j][1] = *(const float4*)(p + 4);
                }
                const float* pb = B + (n0 + sr[j]) * K + kn + sp[j] * 8;
                br[j][0] = *(const float4*)pb; br[j][1] = *(const float4*)(pb + 4);
            }
        }
        #pragma unroll
        for (int kc = 0; kc < 2; ++kc) {
            const int key = ((kc * 4 + lg) ^ (li & 7)) << 4;
            bf16x8 a[4], b[4];
            #pragma unroll
            for (int f = 0; f < 4; ++f)
                a[f] = *(const bf16x8*)&AsB[(wm * 64 + f * 16 + li) * 128 + key];
            #pragma unroll
            for (int f = 0; f < 4; ++f)
                b[f] = *(const bf16x8*)&BsB[(wn * 64 + f * 16 + li) * 128 + key];
            #pragma unroll
            for (int mi = 0; mi < 4; ++mi)
                #pragma unroll
                for (int ni = 0; ni < 4; ++ni)
                    acc[mi][ni] = __builtin_amdgcn_mfma_f32_16x16x32_bf16(a[mi], b[ni], acc[mi][ni], 0, 0, 0);
        }
    }

    const int mb = m0 + wm * 64;
    const int nb0 = n0 + wn * 64;
    if constexpr (EPI == 0) {
        const int part = n0 >> 10;
        if (part < 2) {
            u16* dst = (part == 0) ? q : k;
            const float scl = (part == 0) ? 0.125f : 1.0f;
            #pragma unroll
            for (int mi = 0; mi < 4; ++mi)
                #pragma unroll
                for (int r = 0; r < 4; ++r) {
                    const int m = mb + mi * 16 + lg * 4 + r;
                    const int bb = m >> 11, t = m & 2047;
                    #pragma unroll
                    for (int ni = 0; ni < 4; ++ni) {
                        const int n = nb0 + ni * 16 + li;
                        const int c = n & 1023;
                        const int h = c >> 6, d = c & 63;
                        const float val = (acc[mi][ni][r] + bias[n]) * scl;
                        dst[(((bb << 4) + h) * T_ + t) * DH + d] = f2bf(val);
                    }
                }
        } else {
            // V transposed: vt[((b*16+h)*64 + d)*2048 + t]; 4 consecutive t per store
            #pragma unroll
            for (int mi = 0; mi < 4; ++mi) {
                const int m = mb + mi * 16 + lg * 4;
                const int bb = m >> 11, t0 = m & 2047;
                #pragma unroll
                for (int ni = 0; ni < 4; ++ni) {
                    const int n = nb0 + ni * 16 + li;
                    const int c = n & 1023;
                    const int h = c >> 6, d = c & 63;
                    const float bz = bias[n];
                    u32 w0 = pkbf(acc[mi][ni][0] + bz, acc[mi][ni][1] + bz);
                    u32 w1 = pkbf(acc[mi][ni][2] + bz, acc[mi][ni][3] + bz);
                    *(uint2*)&vt[(((bb << 4) + h) * 64 + d) * (size_t)T_ + t0] = make_uint2(w0, w1);
                }
            }
        }
    } else {
        #pragma unroll
        for (int mi = 0; mi < 4; ++mi)
            #pragma unroll
            for (int r = 0; r < 4; ++r) {
                const int m = mb + mi * 16 + lg * 4 + r;
                #pragma unroll
                for (int ni = 0; ni < 4; ++ni) {
                    const int n = nb0 + ni * 16 + li;
                    outF[m * 1024 + n] = acc[mi][ni][r] + bias[n];
                }
            }
    }
}

// ---------------- MFMA flash attention v3 ----------------
// 512 threads (8 waves), Q-tile 128 (wave w owns rows w*16..w*16+15).
// Grid (32, 8): bh = blockIdx.x (consecutive ids share XCD per bh%8), pair pr = blockIdx.y,
// q-tiles {pr, 15-pr} -> 34 KV-tiles per block, uniform.
// K LDS [k][d] and V LDS [d][k] (from pre-transposed Vt global), both 64x64 bf16,
// 16B-seg swizzle seg^=(row&7), double-buffered. P per-wave 16x128B.
__global__ __launch_bounds__(512, 2) void flash_attn(
    const u16* __restrict__ Q, const u16* __restrict__ K,
    const u16* __restrict__ Vt, const float* __restrict__ unused,
    u16* __restrict__ Y)
{
    __shared__ __align__(16) char KsB[2][8192];
    __shared__ __align__(16) char VsB[2][8192];
    __shared__ __align__(16) char PsB[8][2048];

    const int bh = blockIdx.x;
    const int pr = blockIdx.y;
    const int tid = threadIdx.x;
    const int w  = tid >> 6;
    const int l  = tid & 63;
    const int li = l & 15, lg = l >> 4;
    const u16* Qb = Q  + (size_t)bh * (T_ * DH);
    const u16* Kb = K  + (size_t)bh * (T_ * DH);
    const u16* Vb = Vt + (size_t)bh * (T_ * DH);   // [d][t] rows of T_
    const int srow = tid >> 3;   // 0..63
    const int sseg = tid & 7;    // 16B segment
    char* Pw = PsB[w];
    const int b = bh >> 4, h = bh & 15;
    const int skey = (srow & 7) << 4;
    const int rdkey = (li & 7) << 4;

    #pragma unroll
    for (int ph = 0; ph < 2; ++ph) {
        const int qt = ph ? (15 - pr) : pr;
        const int wq0 = qt * 128 + w * 16;
        const int nkv = 2 * qt + 2;

        bf16x8 qa[2];
        {
            const int qrow = wq0 + li;
            qa[0] = *(const bf16x8*)(Qb + qrow * 64 + 0  + lg * 8);
            qa[1] = *(const bf16x8*)(Qb + qrow * 64 + 32 + lg * 8);
        }
        f32x4 o[4];
        #pragma unroll
        for (int nb = 0; nb < 4; ++nb) o[nb] = (f32x4){0.f, 0.f, 0.f, 0.f};
        float m_r[4], l_r[4];
        #pragma unroll
        for (int r = 0; r < 4; ++r) { m_r[r] = -INFINITY; l_r[r] = 0.f; }

        uint4 kr, vr;
        // ---- prologue: stage tile 0 into buf 0 ----
        kr = *(const uint4*)(Kb + srow * 64 + sseg * 8);
        vr = *(const uint4*)(Vb + srow * (size_t)T_ + sseg * 8);
        *(uint4*)&KsB[0][srow * 128 + ((sseg << 4) ^ skey)] = kr;
        *(uint4*)&VsB[0][srow * 128 + ((sseg << 4) ^ skey)] = vr;
        __syncthreads();

        for (int j = 0; j < nkv; ++j) {
            const int cur = j & 1;
            const bool has_next = (j + 1 < nkv);
            const bool full_mask = (j * 64 >= wq0 + 16);
            // ---- issue next tile's global loads ----
            if (has_next) {
                kr = *(const uint4*)(Kb + ((j + 1) * 64 + srow) * 64 + sseg * 8);
                vr = *(const uint4*)(Vb + srow * (size_t)T_ + (j + 1) * 64 + sseg * 8);
            }
            f32x4 s[4];
            if (!full_mask) {
                // ---- S = Q.K^T ----
                const char* Kc = KsB[cur];
                #pragma unroll
                for (int f = 0; f < 4; ++f) {
                    s[f] = (f32x4){0.f, 0.f, 0.f, 0.f};
                    #pragma unroll
                    for (int c = 0; c < 2; ++c) {
                        bf16x8 kb = *(const bf16x8*)&Kc[(f * 16 + li) * 128 + ((c * 64 + lg * 16) ^ rdkey)];
                        s[f] = __builtin_amdgcn_mfma_f32_16x16x32_bf16(qa[c], kb, s[f], 0, 0, 0);
                    }
                }
                if ((j + 1) * 64 > wq0) {   // diagonal tile for this wave
                    #pragma unroll
                    for (int f = 0; f < 4; ++f)
                        #pragma unroll
                        for (int r = 0; r < 4; ++r)
                            if (j * 64 + f * 16 + li > wq0 + lg * 4 + r) s[f][r] = -INFINITY;
                }
                // ---- online softmax, DPP reductions ----
                #pragma unroll
                for (int r = 0; r < 4; ++r) {
                    float tm = fmaxf(fmaxf(s[0][r], s[1][r]), fmaxf(s[2][r], s[3][r]));
                    tm = redmax16(tm);
                    const float mnew = fmaxf(m_r[r], tm);
                    const float corr = __expf(m_r[r] - mnew);
                    m_r[r] = mnew;
                    float a = 0.f;
                    #pragma unroll
                    for (int f = 0; f < 4; ++f) {
                        const float p = __expf(s[f][r] - mnew);
                        s[f][r] = p;
                        a += p;
                    }
                    l_r[r] = l_r[r] * corr + redsum16(a);
                    #pragma unroll
                    for (int nb = 0; nb < 4; ++nb) o[nb][r] *= corr;
                }
                // ---- P -> per-wave LDS (cvt_pk) ----
                #pragma unroll
                for (int r = 0; r < 4; ++r) {
                    const int row = lg * 4 + r;
                    const int rkey = (row & 7) << 4;
                    const u32 pk0 = pkbf(s[0][r], s[1][r]);
                    const u32 pk1 = pkbf(s[2][r], s[3][r]);
                    *(u16*)&Pw[row * 128 + (((     li) * 2) ^ rkey)] = (u16)pk0;
                    *(u16*)&Pw[row * 128 + (((16 + li) * 2) ^ rkey)] = (u16)(pk0 >> 16);
                    *(u16*)&Pw[row * 128 + (((32 + li) * 2) ^ rkey)] = (u16)pk1;
                    *(u16*)&Pw[row * 128 + (((48 + li) * 2) ^ rkey)] = (u16)(pk1 >> 16);
                }
            }
            // ---- write prefetched K/V into the other buffer ----
            if (has_next) {
                *(uint4*)&KsB[cur ^ 1][srow * 128 + ((sseg << 4) ^ skey)] = kr;
                *(uint4*)&VsB[cur ^ 1][srow * 128 + ((sseg << 4) ^ skey)] = vr;
            }
            // ---- O += P @ V ----
            if (!full_mask) {
                const char* Vc = VsB[cur];
                #pragma unroll
                for (int c = 0; c < 2; ++c) {
                    bf16x8 pa = *(const bf16x8*)&Pw[li * 128 + ((c * 64 + lg * 16) ^ rdkey)];
                    #pragma unroll
                    for (int nb = 0; nb < 4; ++nb) {
                        bf16x8 vb = *(const bf16x8*)&Vc[(nb * 16 + li) * 128 + ((c * 64 + lg * 16) ^ rdkey)];
                        o[nb] = __builtin_amdgcn_mfma_f32_16x16x32_bf16(pa, vb, o[nb], 0, 0, 0);
                    }
                }
            }
            __syncthreads();
        }

        // ---- epilogue: Y in [B,T,C] ----
        #pragma unroll
        for (int r = 0; r < 4; ++r) {
            const float inv = 1.0f / l_r[r];
            const int row = wq0 + lg * 4 + r;
            u16* yp = Y + ((size_t)(b * T_ + row) * 1024) + h * DH + li;
            #pragma unroll
            for (int nb = 0; nb < 4; ++nb)
                yp[nb * 16] = f2bf(o[nb][r] * inv);
        }
    }
}

extern "C" void kernel_launch(void* const* d_in, const int* in_sizes, int n_in,
                              void* d_out, int out_size, void* d_ws, size_t ws_size,
                              hipStream_t stream) {
    const float* x      = (const float*)d_in[0];
    const float* W_attn = (const float*)d_in[1];
    const float* b_attn = (const float*)d_in[2];
    const float* W_proj = (const float*)d_in[3];
    const float* b_proj = (const float*)d_in[4];
    float* out = (float*)d_out;

    u16* q  = (u16*)d_ws;      // [B,H,T,D]
    u16* k  = q + NQ;          // [B,H,T,D]
    u16* vt = k + NQ;          // [B,H,D,T]  (transposed)
    u16* y  = vt + NQ;         // [B,T,C]

    gemm_bt<0><<<dim3(24, 32), 256, 0, stream>>>(x, W_attn, b_attn, q, k, vt, nullptr);
    flash_attn<<<dim3(32, 8), 512, 0, stream>>>(q, k, vt, nullptr, y);
    gemm_bt<1><<<dim3(8, 32), 256, 0, stream>>>(y, W_proj, b_proj, nullptr, nullptr, nullptr, out);
}